// Round 13
// baseline (86.979 us; speedup 1.0000x reference)
//
#include <hip/hip_runtime.h>
#include <hip/hip_bf16.h>

// out[8192,1024] = x[8192,1024] @ W[1024,1024]^T + b  (fp32 in/out, bf16 MFMA)
// v13: A (x) bypasses LDS entirely -> per-fragment direct global->reg f32
// loads + in-reg cvt (2-step prefetch distance). Only B (W) staged in LDS:
// 3-buffer rotation, 2-step load->write distance, v6-verified zero-conflict
// swizzle. Raw lgkmcnt barriers only (vmcnt never drained). BM=256 x BN=128,
// BK=32, 512 thr / 8 waves as 4Mx2N (wave 64x64), grid 256, XCD-exclusive
// m-panels. v10-validated transposed-C epilogue (f32x4 stores).

typedef float f32x4 __attribute__((ext_vector_type(4)));
typedef __bf16 bf16x8 __attribute__((ext_vector_type(8)));
typedef unsigned short u16x4 __attribute__((ext_vector_type(4)));
typedef unsigned short u16x8 __attribute__((ext_vector_type(8)));

#define MD 8192
#define ND 1024
#define KD 1024
#define BM 256
#define BN 128
#define BK 32
#define NT (KD / BK)     // 32 K-steps
#define THREADS 512

__device__ __forceinline__ u16x4 cvt4(f32x4 v) {
  u16x4 o;
#pragma unroll
  for (int i = 0; i < 4; ++i) o[i] = __builtin_bit_cast(unsigned short, (__bf16)v[i]);
  return o;
}
__device__ __forceinline__ bf16x8 cvt8(f32x4 lo, f32x4 hi) {
  u16x8 o;
#pragma unroll
  for (int j = 0; j < 4; ++j) {
    o[j]     = __builtin_bit_cast(unsigned short, (__bf16)lo[j]);
    o[4 + j] = __builtin_bit_cast(unsigned short, (__bf16)hi[j]);
  }
  return __builtin_bit_cast(bf16x8, o);
}

// raw barrier: LDS completion only; global loads stay in flight (counted vmcnt)
#define BAR()                                            \
  do {                                                   \
    asm volatile("s_waitcnt lgkmcnt(0)" ::: "memory");   \
    __builtin_amdgcn_sched_barrier(0);                   \
    __builtin_amdgcn_s_barrier();                        \
    __builtin_amdgcn_sched_barrier(0);                   \
  } while (0)

__global__ __launch_bounds__(THREADS, 2)
void linear_mfma_v13(const float* __restrict__ X, const float* __restrict__ W,
                     const float* __restrict__ Bv, float* __restrict__ C) {
  __shared__ __align__(16) char Bsm[3][BN * BK * 2];   // 3 x 8 KB

  const int bid = blockIdx.x;
  const int xcd = bid & 7;                 // dispatch round-robins XCDs by bid&7
  const int ord = bid >> 3;                // 0..31
  const int mtile = xcd * 4 + (ord >> 3);  // 4 XCD-exclusive m-panels per XCD
  const int ntile = ord & 7;
  const int brow = mtile * BM;
  const int bcol = ntile * BN;

  const int t = threadIdx.x;
  const int lane = t & 63;
  const int w = t >> 6;      // 0..7
  const int wm = w >> 1;     // 0..3 : 64-row quarter of BM
  const int wn = w & 1;      // 0..1 : 64-col half of BN

  // ---- A direct-from-global: lane l covers row (l&15) of each 16-row m-frag,
  // floats (l>>4)*8 .. +7 of the K-step. 2 f32x4 per frag.
  const float* gAw = X + (size_t)(brow + wm * 64 + (lane & 15)) * KD + ((lane >> 4) * 8);

  // ---- B staging map (v6-verified swizzle): 1024 chunks (128 rows x 8 f32x4),
  // 512 threads x 2 chunks. chunk q -> row=q>>3, sc=q&7.
  const float* gB[2]; int woffB[2];
#pragma unroll
  for (int i = 0; i < 2; ++i) {
    int q = t + i * THREADS;
    int row = q >> 3, sc = q & 7;
    int kq = sc >> 1, h = sc & 1;
    gB[i] = W + (size_t)(bcol + row) * KD + sc * 4;
    woffB[i] = (row >> 4) * 1024 + ((((kq << 8) + ((row & 15) << 4) + (h << 3))) ^ (kq << 5));
  }
  // B fragment read offset (16B/lane, swizzle-mirrored; verified conflict-free)
  const int fr = (lane * 16) ^ ((lane >> 4) << 5);

  // prefetch register sets (static names; 2-step distance both paths)
  f32x4 pa0[8], pa1[8];    // A: even/odd step sets
  f32x4 pb0[2], pb1[2];    // B: set0 holds even-indexed B tiles, set1 odd

#define LOADA0(kt)                                                           \
  do { _Pragma("unroll") for (int m = 0; m < 4; ++m) {                       \
      const float* p = gAw + (size_t)m * 16 * KD + (size_t)(kt) * BK;        \
      pa0[2 * m] = *(const f32x4*)p; pa0[2 * m + 1] = *(const f32x4*)(p + 4); } } while (0)
#define LOADA1(kt)                                                           \
  do { _Pragma("unroll") for (int m = 0; m < 4; ++m) {                       \
      const float* p = gAw + (size_t)m * 16 * KD + (size_t)(kt) * BK;        \
      pa1[2 * m] = *(const f32x4*)p; pa1[2 * m + 1] = *(const f32x4*)(p + 4); } } while (0)
#define LOADB0(kt)                                                           \
  do { _Pragma("unroll") for (int i = 0; i < 2; ++i)                         \
      pb0[i] = *(const f32x4*)(gB[i] + (size_t)(kt) * BK); } while (0)
#define LOADB1(kt)                                                           \
  do { _Pragma("unroll") for (int i = 0; i < 2; ++i)                         \
      pb1[i] = *(const f32x4*)(gB[i] + (size_t)(kt) * BK); } while (0)
#define WRITEB0(buf)                                                         \
  do { _Pragma("unroll") for (int i = 0; i < 2; ++i)                         \
      *(u16x4*)&Bsm[buf][woffB[i]] = cvt4(pb0[i]); } while (0)
#define WRITEB1(buf)                                                         \
  do { _Pragma("unroll") for (int i = 0; i < 2; ++i)                         \
      *(u16x4*)&Bsm[buf][woffB[i]] = cvt4(pb1[i]); } while (0)

  f32x4 acc[4][4] = {};   // transposed C/D fragments (v10-validated)

#define COMPUTE(buf, PA)                                                        \
  do {                                                                          \
    bf16x8 am[4];                                                               \
    _Pragma("unroll") for (int m = 0; m < 4; ++m)                               \
      am[m] = cvt8(PA[2 * m], PA[2 * m + 1]);                                   \
    bf16x8 bf[4];                                                               \
    _Pragma("unroll") for (int n = 0; n < 4; ++n)                               \
      bf[n] = __builtin_bit_cast(bf16x8,                                        \
          *(const u16x8*)(&Bsm[buf][(wn * 4 + n) * 1024 + fr]));                \
    __builtin_amdgcn_s_setprio(1);                                              \
    _Pragma("unroll") for (int m = 0; m < 4; ++m)                               \
      _Pragma("unroll") for (int n = 0; n < 4; ++n)                             \
        acc[m][n] = __builtin_amdgcn_mfma_f32_16x16x32_bf16(bf[n], am[m],       \
                                                            acc[m][n], 0, 0, 0);\
    __builtin_amdgcn_s_setprio(0);                                              \
  } while (0)

  // ---- prologue: B(0)->set0->buf0, B(1)->set1, B(2)->set0; A(0),A(1)
  LOADB0(0);
  LOADB1(1);
  LOADA0(0);
  LOADA1(1);
  WRITEB0(0);            // B(0) -> buf0 (counted vmcnt; later loads in flight)
  LOADB0(2);             // set0 freed -> load B(2)
  BAR();

  // ---- main loop: 2 steps/iter. Step kt: read B buf[kt%3], consume A set,
  // write B(kt+1) from set((kt+1)&1) into buf[(kt+1)%3], reload that set with
  // B(kt+3). A set reloaded with A(kt+2). All loads: 2-step distance.
#pragma unroll 1
  for (int kt2 = 0; kt2 < NT / 2; ++kt2) {
    const int kt = 2 * kt2;
    {  // EVEN step kt: A=pa0, B buf[kt%3]; B(kt+1) in set1
      const int rb = kt % 3, wb = (kt + 1) % 3;
      bf16x8 am0[4];
#pragma unroll
      for (int m = 0; m < 4; ++m) am0[m] = cvt8(pa0[2 * m], pa0[2 * m + 1]);
      if (kt + 2 < NT) LOADA0(kt + 2);
      WRITEB1(wb);
      if (kt + 3 < NT) LOADB1(kt + 3);
      bf16x8 bf[4];
#pragma unroll
      for (int n = 0; n < 4; ++n)
        bf[n] = __builtin_bit_cast(bf16x8,
            *(const u16x8*)(&Bsm[rb][(wn * 4 + n) * 1024 + fr]));
      __builtin_amdgcn_s_setprio(1);
#pragma unroll
      for (int m = 0; m < 4; ++m)
#pragma unroll
        for (int n = 0; n < 4; ++n)
          acc[m][n] = __builtin_amdgcn_mfma_f32_16x16x32_bf16(bf[n], am0[m],
                                                              acc[m][n], 0, 0, 0);
      __builtin_amdgcn_s_setprio(0);
      BAR();
    }
    {  // ODD step kt+1: A=pa1, B buf[(kt+1)%3]; B(kt+2) in set0
      const int rb = (kt + 1) % 3, wb = (kt + 2) % 3;
      bf16x8 am1[4];
#pragma unroll
      for (int m = 0; m < 4; ++m) am1[m] = cvt8(pa1[2 * m], pa1[2 * m + 1]);
      if (kt + 3 < NT) LOADA1(kt + 3);
      if (kt + 2 < NT) WRITEB0(wb);
      if (kt + 4 < NT) LOADB0(kt + 4);
      bf16x8 bf[4];
#pragma unroll
      for (int n = 0; n < 4; ++n)
        bf[n] = __builtin_bit_cast(bf16x8,
            *(const u16x8*)(&Bsm[rb][(wn * 4 + n) * 1024 + fr]));
      __builtin_amdgcn_s_setprio(1);
#pragma unroll
      for (int m = 0; m < 4; ++m)
#pragma unroll
        for (int n = 0; n < 4; ++n)
          acc[m][n] = __builtin_amdgcn_mfma_f32_16x16x32_bf16(bf[n], am1[m],
                                                              acc[m][n], 0, 0, 0);
      __builtin_amdgcn_s_setprio(0);
      BAR();
    }
  }

  // ---- epilogue (transposed fragments, v10-validated): lane owns C row
  // rbase+m*16, 4 consecutive cols cbase+n*16.. -> f32x4 stores, bias f32x4.
  const int rbase = brow + wm * 64 + (lane & 15);
  const int cbase = bcol + wn * 64 + ((lane >> 4) << 2);
#pragma unroll
  for (int n = 0; n < 4; ++n) {
    const int col = cbase + n * 16;
    const f32x4 bv4 = *(const f32x4*)&Bv[col];
#pragma unroll
    for (int m = 0; m < 4; ++m) {
      const int row = rbase + m * 16;
      f32x4 v = acc[m][n] + bv4;
      *(f32x4*)&C[(size_t)row * ND + col] = v;
    }
  }
}

extern "C" void kernel_launch(void* const* d_in, const int* in_sizes, int n_in,
                              void* d_out, int out_size, void* d_ws, size_t ws_size,
                              hipStream_t stream) {
  const float* x = (const float*)d_in[0];   // [8192,1024] f32
  const float* W = (const float*)d_in[1];   // [1024,1024] f32
  const float* b = (const float*)d_in[2];   // [1024] f32
  float* out = (float*)d_out;               // [8192,1024] f32

  dim3 grid((MD / BM) * (ND / BN));   // 32 * 8 = 256 blocks = 1 per CU
  dim3 block(THREADS);
  hipLaunchKernelGGL(linear_mfma_v13, grid, block, 0, stream, x, W, b, out);
}

// Round 14
// 34.940 us; speedup vs baseline: 2.4894x; 2.4894x over previous
//
#include <hip/hip_runtime.h>
#include <hip/hip_bf16.h>

// out[8192,1024] = x[8192,1024] @ W[1024,1024]^T + b  (fp32 in/out, bf16 MFMA)
// v14: producer-consumer wave specialization on v6 geometry.
// 512 thr / 8 waves: waves 0-3 PRODUCERS (global f32 -> cvt -> swizzled LDS,
// depth-2 named-set prefetch, counted vmcnt, never touch MFMA), waves 4-7
// CONSUMERS (2x2 of 64x64: 8 ds_read_b128 + 16 MFMA per step, never touch
// VMEM). ONE raw barrier per K-step (33 total). BM=BN=128, BK=32, grid 512
// (2 blocks/CU), XCD-exclusive m-panels, v6-verified zero-conflict swizzle,
// v10-validated transposed-C f32x4 epilogue.

typedef float f32x4 __attribute__((ext_vector_type(4)));
typedef __bf16 bf16x8 __attribute__((ext_vector_type(8)));
typedef unsigned short u16x4 __attribute__((ext_vector_type(4)));
typedef unsigned short u16x8 __attribute__((ext_vector_type(8)));

#define MD 8192
#define ND 1024
#define KD 1024
#define BM 128
#define BN 128
#define BK 32
#define NT (KD / BK)     // 32 K-steps
#define THREADS 512

__device__ __forceinline__ u16x4 cvt4(f32x4 v) {
  u16x4 o;
#pragma unroll
  for (int i = 0; i < 4; ++i) o[i] = __builtin_bit_cast(unsigned short, (__bf16)v[i]);
  return o;
}

// raw barrier: own-LDS completion only; global loads stay in flight
#define BAR()                                            \
  do {                                                   \
    asm volatile("s_waitcnt lgkmcnt(0)" ::: "memory");   \
    __builtin_amdgcn_sched_barrier(0);                   \
    __builtin_amdgcn_s_barrier();                        \
    __builtin_amdgcn_sched_barrier(0);                   \
  } while (0)

__global__ __launch_bounds__(THREADS, 4)
void linear_mfma_v14(const float* __restrict__ X, const float* __restrict__ W,
                     const float* __restrict__ Bv, float* __restrict__ C) {
  // 16-row stripes of 1024B; within-stripe byte = ((kq<<8)+(r16<<4)+(h<<3)) ^ (kq<<5)
  // (kq=k>>3, h=(k>>2)&1). Verified conflict-free write+read (v3..v11: 0 conflicts).
  __shared__ __align__(16) char Asm[2][BM * BK * 2];   // 8 KB each
  __shared__ __align__(16) char Bsm[2][BN * BK * 2];   // 8 KB each

  const int bid = blockIdx.x;
  const int xcd = bid & 7;                 // dispatch round-robins XCDs by bid&7
  const int ord = bid >> 3;                // 0..63
  const int mtile = xcd * 8 + (ord >> 3);  // 8 XCD-exclusive m-panels per XCD
  const int ntile = ord & 7;
  const int brow = mtile * BM;
  const int bcol = ntile * BN;

  const int t = threadIdx.x;
  const int lane = t & 63;
  const int w = t >> 6;      // 0..7

  if (w < 4) {
    // ================= PRODUCER waves 0-3 (256 threads) =================
    // staging map: q = t + i*256 -> (row = q>>3, sc = q&7); f32x4 at k = sc*4
    const float* gA[4];
    const float* gB[4];
    int woff[4];
#pragma unroll
    for (int i = 0; i < 4; ++i) {
      int q = t + i * 256;                 // 0..1023 -> 128 rows x 8 chunks
      int row = q >> 3, sc = q & 7;
      int kq = sc >> 1, h = sc & 1;
      gA[i] = X + (size_t)(brow + row) * KD + sc * 4;
      gB[i] = W + (size_t)(bcol + row) * KD + sc * 4;
      woff[i] = (row >> 4) * 1024 +
                ((((kq << 8) + ((row & 15) << 4) + (h << 3))) ^ (kq << 5));
    }

    // depth-2 named prefetch sets: set s holds tiles with parity s
    f32x4 pa0[4], pb0[4], pa1[4], pb1[4];

#define LOADSET0(kt)                                                      \
    do {                                                                  \
      _Pragma("unroll") for (int i = 0; i < 4; ++i)                       \
          pa0[i] = *(const f32x4*)(gA[i] + (size_t)(kt) * BK);            \
      _Pragma("unroll") for (int i = 0; i < 4; ++i)                       \
          pb0[i] = *(const f32x4*)(gB[i] + (size_t)(kt) * BK);            \
    } while (0)
#define LOADSET1(kt)                                                      \
    do {                                                                  \
      _Pragma("unroll") for (int i = 0; i < 4; ++i)                       \
          pa1[i] = *(const f32x4*)(gA[i] + (size_t)(kt) * BK);            \
      _Pragma("unroll") for (int i = 0; i < 4; ++i)                       \
          pb1[i] = *(const f32x4*)(gB[i] + (size_t)(kt) * BK);            \
    } while (0)
#define WRITESET0(buf)                                                    \
    do {                                                                  \
      _Pragma("unroll") for (int i = 0; i < 4; ++i)                       \
          *(u16x4*)&Asm[buf][woff[i]] = cvt4(pa0[i]);                     \
      _Pragma("unroll") for (int i = 0; i < 4; ++i)                       \
          *(u16x4*)&Bsm[buf][woff[i]] = cvt4(pb0[i]);                     \
    } while (0)
#define WRITESET1(buf)                                                    \
    do {                                                                  \
      _Pragma("unroll") for (int i = 0; i < 4; ++i)                       \
          *(u16x4*)&Asm[buf][woff[i]] = cvt4(pa1[i]);                     \
      _Pragma("unroll") for (int i = 0; i < 4; ++i)                       \
          *(u16x4*)&Bsm[buf][woff[i]] = cvt4(pb1[i]);                     \
    } while (0)

    // prologue: t0->set0->buf0, t1->set1, refill set0 with t2
    LOADSET0(0);
    LOADSET1(1);
    WRITESET0(0);          // counted vmcnt(8): set1's loads stay in flight
    LOADSET0(2);
    BAR();                 // barrier #0: buf0 (tile0) published

    // main loop: 2 K-steps per iteration, ONE barrier per step.
    // During consumer step kt, producers write tile kt+1 -> buf[(kt+1)&1].
#pragma unroll 1
    for (int kt2 = 0; kt2 < NT / 2; ++kt2) {
      const int kt = 2 * kt2;
      // consumer step kt (even): write tile kt+1 from set1, refill set1 <- kt+3
      WRITESET1(1);
      if (kt + 3 < NT) LOADSET1(kt + 3);
      BAR();
      // consumer step kt+1 (odd): write tile kt+2 from set0, refill set0 <- kt+4
      if (kt + 2 < NT) WRITESET0(0);
      if (kt + 4 < NT) LOADSET0(kt + 4);
      BAR();
    }
    // producers exit (no C writes)
  } else {
    // ================= CONSUMER waves 4-7 =================
    const int cw = w - 4;
    const int wm = cw >> 1;    // 0..1 : 64-row half
    const int wn = cw & 1;     // 0..1 : 64-col half
    const int fr = (lane * 16) ^ ((lane >> 4) << 5);   // swizzle-mirrored frag read

    f32x4 acc[4][4] = {};      // transposed C/D fragments (v10-validated)

    BAR();                     // barrier #0: buf0 ready
#pragma unroll 1
    for (int kt = 0; kt < NT; ++kt) {
      const int buf = kt & 1;
      bf16x8 bf[4], am[4];
#pragma unroll
      for (int n = 0; n < 4; ++n)
        bf[n] = __builtin_bit_cast(bf16x8,
            *(const u16x8*)(&Bsm[buf][(wn * 4 + n) * 1024 + fr]));
#pragma unroll
      for (int m = 0; m < 4; ++m)
        am[m] = __builtin_bit_cast(bf16x8,
            *(const u16x8*)(&Asm[buf][(wm * 4 + m) * 1024 + fr]));
      __builtin_amdgcn_s_setprio(1);
#pragma unroll
      for (int m = 0; m < 4; ++m)
#pragma unroll
        for (int n = 0; n < 4; ++n)
          acc[m][n] = __builtin_amdgcn_mfma_f32_16x16x32_bf16(bf[n], am[m],
                                                              acc[m][n], 0, 0, 0);
      __builtin_amdgcn_s_setprio(0);
      BAR();                   // step barrier (matches producer)
    }

    // epilogue (transposed fragments): lane owns C row rbase+m*16 and 4
    // consecutive cols cbase+n*16.. -> f32x4 stores, bias folded as f32x4.
    const int rbase = brow + wm * 64 + (lane & 15);
    const int cbase = bcol + wn * 64 + ((lane >> 4) << 2);
#pragma unroll
    for (int n = 0; n < 4; ++n) {
      const int col = cbase + n * 16;
      const f32x4 bv4 = *(const f32x4*)&Bv[col];
#pragma unroll
      for (int m = 0; m < 4; ++m) {
        const int row = rbase + m * 16;
        f32x4 v = acc[m][n] + bv4;
        *(f32x4*)&C[(size_t)row * ND + col] = v;
      }
    }
  }
}

extern "C" void kernel_launch(void* const* d_in, const int* in_sizes, int n_in,
                              void* d_out, int out_size, void* d_ws, size_t ws_size,
                              hipStream_t stream) {
  const float* x = (const float*)d_in[0];   // [8192,1024] f32
  const float* W = (const float*)d_in[1];   // [1024,1024] f32
  const float* b = (const float*)d_in[2];   // [1024] f32
  float* out = (float*)d_out;               // [8192,1024] f32

  dim3 grid((MD / BM) * (ND / BN));   // 64 * 8 = 512 -> 2 blocks per CU
  dim3 block(THREADS);
  hipLaunchKernelGGL(linear_mfma_v14, grid, block, 0, stream, x, W, b, out);
}